// Round 1
// baseline (902.849 us; speedup 1.0000x reference)
//
#include <hip/hip_runtime.h>

typedef __bf16 bf16_t;
typedef __bf16 bf16x8 __attribute__((ext_vector_type(8)));
typedef float f32x4 __attribute__((ext_vector_type(4)));

#define MFMA_BF16(a, b, c) __builtin_amdgcn_mfma_f32_16x16x32_bf16((a), (b), (c), 0, 0, 0)

static constexpr int Bn = 4096;
static constexpr int Dn = 1024;
static constexpr int Rn = 256;
static constexpr int BT = 16;          // rows per block (one MFMA M-tile)
static constexpr int XV_STRIDE = 1032; // bf16 elems; 1032*2=2064 B rows: 16B-aligned, stride%32dw==4 -> 2-way (free)
static constexpr int T_STRIDE = 264;   // same trick for the T tile
static constexpr float DTv = 0.01f;
static constexpr float HDT = 0.005f;

// ---- Pack U [D=1024, R=256] fp32 -> bf16 B-operand fragment layout ----
// Upk[((ct*32 + kb)*64 + lane)*8 + j] = U[kb*32 + (lane>>4)*8 + j][ct*16 + (lane&15)]
__global__ void pack_u_kernel(const float* __restrict__ U, bf16_t* __restrict__ Upk) {
  int t = blockIdx.x * blockDim.x + threadIdx.x;  // 16*32*64 = 32768 threads
  int l = t & 63;
  int f = t >> 6;
  int kb = f & 31;
  int ct = f >> 5;
  int row0 = kb * 32 + (l >> 4) * 8;
  int col = ct * 16 + (l & 15);
  bf16x8 v;
#pragma unroll
  for (int j = 0; j < 8; ++j) v[j] = (bf16_t)U[(size_t)(row0 + j) * Rn + col];
  ((bf16x8*)Upk)[t] = v;
}

// ---- Pack W [R=256, D=1024] fp32 -> bf16 B-operand fragment layout ----
// Wpk[((ct*8 + kb)*64 + lane)*8 + j] = W[kb*32 + (lane>>4)*8 + j][ct*16 + (lane&15)]
__global__ void pack_w_kernel(const float* __restrict__ W, bf16_t* __restrict__ Wpk) {
  int t = blockIdx.x * blockDim.x + threadIdx.x;  // 64*8*64 = 32768 threads
  int l = t & 63;
  int f = t >> 6;
  int kb = f & 7;
  int ct = f >> 3;
  int row0 = kb * 32 + (l >> 4) * 8;
  int col = ct * 16 + (l & 15);
  bf16x8 v;
#pragma unroll
  for (int j = 0; j < 8; ++j) v[j] = (bf16_t)W[(size_t)(row0 + j) * Dn + col];
  ((bf16x8*)Wpk)[t] = v;
}

// ---- Fused symplectic integrator: one block owns 16 rows for all steps ----
__global__ __launch_bounds__(512, 2)
void integrate_kernel(const float* __restrict__ x_in, const float* __restrict__ v_in,
                      const float* __restrict__ force,
                      const bf16_t* __restrict__ Upk, const bf16_t* __restrict__ Wpk,
                      const int* __restrict__ steps_p, float* __restrict__ out) {
  extern __shared__ __align__(16) char lds[];
  bf16_t* xbf = (bf16_t*)lds;                 // [16][1032]
  bf16_t* vbf = xbf + BT * XV_STRIDE;         // [16][1032]
  bf16_t* tbf = vbf + BT * XV_STRIDE;         // [16][264]

  const int tid = (int)threadIdx.x;
  const int w = tid >> 6;   // wave 0..7
  const int l = tid & 63;
  const int ln = l & 15;
  const int quad = l >> 4;  // 0..3
  const int nhalf = 2 * steps_p[0];
  const int row_base = (int)blockIdx.x * BT;

  // fp32 master state in registers, MFMA C/D layout:
  //   element (j, r) <-> local row = quad*4 + r, col = (w*8 + j)*16 + ln
  float xs[8][4], vs[8][4];

#pragma unroll
  for (int j = 0; j < 8; ++j) {
    const int col = (w * 8 + j) * 16 + ln;
#pragma unroll
    for (int r = 0; r < 4; ++r) {
      const size_t g = (size_t)(row_base + quad * 4 + r) * Dn + col;
      xs[j][r] = x_in[g];
      vs[j][r] = v_in[g];
    }
  }

  // initial bf16 tiles
#pragma unroll
  for (int j = 0; j < 8; ++j) {
    const int col = (w * 8 + j) * 16 + ln;
#pragma unroll
    for (int r = 0; r < 4; ++r) {
      const int row = quad * 4 + r;
      xbf[row * XV_STRIDE + col] = (bf16_t)xs[j][r];
      vbf[row * XV_STRIDE + col] = (bf16_t)vs[j][r];
    }
  }
  __syncthreads();

  for (int h = 0; h < nhalf; ++h) {
    // ---- phase 1: Hx = x@U, Hv = v@U for column tiles {2w, 2w+1} ----
    f32x4 hx0 = {0.f, 0.f, 0.f, 0.f}, hx1 = {0.f, 0.f, 0.f, 0.f};
    f32x4 hv0 = {0.f, 0.f, 0.f, 0.f}, hv1 = {0.f, 0.f, 0.f, 0.f};
    {
      const bf16x8* up = (const bf16x8*)Upk;
      const int c0 = w * 2;
      const bf16_t* xrow = xbf + ln * XV_STRIDE + quad * 8;
      const bf16_t* vrow = vbf + ln * XV_STRIDE + quad * 8;
      bf16x8 b0 = up[(c0 * 32 + 0) * 64 + l];
      bf16x8 b1 = up[((c0 + 1) * 32 + 0) * 64 + l];
#pragma unroll
      for (int kb = 0; kb < 32; ++kb) {
        const bf16x8 ax = *(const bf16x8*)(xrow + kb * 32);
        const bf16x8 av = *(const bf16x8*)(vrow + kb * 32);
        bf16x8 nb0 = b0, nb1 = b1;
        if (kb < 31) {
          nb0 = up[(c0 * 32 + kb + 1) * 64 + l];
          nb1 = up[((c0 + 1) * 32 + kb + 1) * 64 + l];
        }
        hx0 = MFMA_BF16(ax, b0, hx0);
        hv0 = MFMA_BF16(av, b0, hv0);
        hx1 = MFMA_BF16(ax, b1, hx1);
        hv1 = MFMA_BF16(av, b1, hv1);
        b0 = nb0;
        b1 = nb1;
      }
    }
    // epilogue: T = tanh(Hx) * Hv^2  (fp32), write bf16 into tbf
#pragma unroll
    for (int i = 0; i < 2; ++i) {
      const f32x4 hx = i ? hx1 : hx0;
      const f32x4 hv = i ? hv1 : hv0;
      const int col = (w * 2 + i) * 16 + ln;
#pragma unroll
      for (int r = 0; r < 4; ++r) {
        float a = hx[r];
        a = fminf(fmaxf(a, -15.f), 15.f);
        const float e = __expf(2.f * a);
        const float gate = (e - 1.f) / (e + 1.f);  // tanh(a)
        const float tval = gate * hv[r] * hv[r];
        tbf[(quad * 4 + r) * T_STRIDE + col] = (bf16_t)tval;
      }
    }
    __syncthreads();

    // ---- phase 2: gamma = T @ W, column tiles w*8 + ch*4 + i; fused update ----
    const bool even = ((h & 1) == 0);
#pragma unroll
    for (int ch = 0; ch < 2; ++ch) {
      f32x4 acc0 = {0.f, 0.f, 0.f, 0.f}, acc1 = {0.f, 0.f, 0.f, 0.f};
      f32x4 acc2 = {0.f, 0.f, 0.f, 0.f}, acc3 = {0.f, 0.f, 0.f, 0.f};
      const bf16x8* wp = (const bf16x8*)Wpk;
      const int ct0 = w * 8 + ch * 4;
      const bf16_t* trow = tbf + ln * T_STRIDE + quad * 8;
      bf16x8 w0 = wp[((ct0 + 0) * 8 + 0) * 64 + l];
      bf16x8 w1 = wp[((ct0 + 1) * 8 + 0) * 64 + l];
      bf16x8 w2 = wp[((ct0 + 2) * 8 + 0) * 64 + l];
      bf16x8 w3 = wp[((ct0 + 3) * 8 + 0) * 64 + l];
#pragma unroll
      for (int kb = 0; kb < 8; ++kb) {
        const bf16x8 at = *(const bf16x8*)(trow + kb * 32);
        bf16x8 n0 = w0, n1 = w1, n2 = w2, n3 = w3;
        if (kb < 7) {
          n0 = wp[((ct0 + 0) * 8 + kb + 1) * 64 + l];
          n1 = wp[((ct0 + 1) * 8 + kb + 1) * 64 + l];
          n2 = wp[((ct0 + 2) * 8 + kb + 1) * 64 + l];
          n3 = wp[((ct0 + 3) * 8 + kb + 1) * 64 + l];
        }
        acc0 = MFMA_BF16(at, w0, acc0);
        acc1 = MFMA_BF16(at, w1, acc1);
        acc2 = MFMA_BF16(at, w2, acc2);
        acc3 = MFMA_BF16(at, w3, acc3);
        w0 = n0; w1 = n1; w2 = n2; w3 = n3;
      }
      // fused velocity/position update for this chunk's columns
#pragma unroll
      for (int i = 0; i < 4; ++i) {
        const f32x4 acc = (i == 0) ? acc0 : (i == 1) ? acc1 : (i == 2) ? acc2 : acc3;
        const int j = ch * 4 + i;
        const int col = (w * 8 + j) * 16 + ln;
#pragma unroll
        for (int r = 0; r < 4; ++r) {
          const size_t g = (size_t)(row_base + quad * 4 + r) * Dn + col;
          const float a = force[g] - acc[r];  // a = force - gamma
          vs[j][r] += HDT * a;
          if (even) xs[j][r] += DTv * vs[j][r];
        }
      }
    }
    // refresh bf16 tiles (v always changed; x only on even half-steps)
#pragma unroll
    for (int j = 0; j < 8; ++j) {
      const int col = (w * 8 + j) * 16 + ln;
#pragma unroll
      for (int r = 0; r < 4; ++r) {
        const int row = quad * 4 + r;
        vbf[row * XV_STRIDE + col] = (bf16_t)vs[j][r];
        if (even) xbf[row * XV_STRIDE + col] = (bf16_t)xs[j][r];
      }
    }
    __syncthreads();
  }

  // ---- store: out = [x (B*D) | v (B*D)] fp32 ----
  float* out_x = out;
  float* out_v = out + (size_t)Bn * Dn;
#pragma unroll
  for (int j = 0; j < 8; ++j) {
    const int col = (w * 8 + j) * 16 + ln;
#pragma unroll
    for (int r = 0; r < 4; ++r) {
      const size_t g = (size_t)(row_base + quad * 4 + r) * Dn + col;
      out_x[g] = xs[j][r];
      out_v[g] = vs[j][r];
    }
  }
}

extern "C" void kernel_launch(void* const* d_in, const int* in_sizes, int n_in,
                              void* d_out, int out_size, void* d_ws, size_t ws_size,
                              hipStream_t stream) {
  const float* x = (const float*)d_in[0];
  const float* v = (const float*)d_in[1];
  const float* force = (const float*)d_in[2];
  const float* U = (const float*)d_in[3];
  const float* W = (const float*)d_in[4];
  const int* steps = (const int*)d_in[5];

  bf16_t* Upk = (bf16_t*)d_ws;                              // 512 KB
  bf16_t* Wpk = (bf16_t*)((char*)d_ws + 16 * 32 * 64 * 8 * 2);  // next 512 KB

  pack_u_kernel<<<128, 256, 0, stream>>>(U, Upk);
  pack_w_kernel<<<128, 256, 0, stream>>>(W, Wpk);

  const size_t lds_bytes = (size_t)(2 * BT * XV_STRIDE + BT * T_STRIDE) * sizeof(bf16_t);  // 74496
  integrate_kernel<<<Bn / BT, 512, lds_bytes, stream>>>(x, v, force, Upk, Wpk, steps, (float*)d_out);
}